// Round 3
// baseline (310.799 us; speedup 1.0000x reference)
//
#include <hip/hip_runtime.h>
#include <math.h>

#define BB 16
#define TT 50
#define AA 3
#define CC 80
#define BA_ 85
#define HH 76
#define WW 76
#define SPAT (HH * WW)          // 5776

__constant__ float c_aw[3] = {1.25f, 2.0f, 4.125f};   // anchors / stride(=8)
__constant__ float c_ah[3] = {1.625f, 3.75f, 2.875f};

__device__ inline float wave_red(float v) {
    #pragma unroll
    for (int off = 32; off; off >>= 1) v += __shfl_down(v, off);
    return v;
}

// One thread per (b, i, j) spatial cell; handles all 3 anchors.
// Recomputes the build_targets scatter state by scanning this batch's 50
// targets (staged in LDS). No big scratch needed.
__global__ void k_loss(const float* __restrict__ pred,
                       const float* __restrict__ targets,
                       float* __restrict__ acc) {
    const int b = blockIdx.y;
    const int s = blockIdx.x * blockDim.x + threadIdx.x;

    __shared__ float tb[TT * 5];                 // this batch's targets
    if (threadIdx.x < TT * 5)
        tb[threadIdx.x] = targets[(size_t)b * TT * 5 + threadIdx.x];
    __syncthreads();

    float s_mse = 0.f, s_bo = 0.f, s_bn = 0.f, s_bc = 0.f, s_co = 0.f, s_cn = 0.f;

    if (s < SPAT) {
        const int i = s / WW;        // H index of this cell
        const int j = s % WW;        // W index of this cell

        int cleared = 0;             // bit a: noobj[b,a,i,j] cleared
        int owner[3] = {-1, -1, -1}; // last valid writer t per anchor
        unsigned cmask[3][3] = {{0u,0u,0u},{0u,0u,0u},{0u,0u,0u}}; // class union

        for (int t = 0; t < TT; ++t) {
            float gx = tb[t * 5 + 0] * WW;
            float gy = tb[t * 5 + 1] * HH;
            float gw = tb[t * 5 + 2] * WW;
            float gh = tb[t * 5 + 3] * HH;
            int cls  = (int)tb[t * 5 + 4];
            if (gx + gy + gw + gh == 0.0f) continue;  // invalid target

            int gi = (int)floorf(gx); if (gi == 0) gi = 1;
            int gj = (int)floorf(gy); if (gj == 0) gj = 1;

            float ious[3];
            float bi = -1.0f; int best = 0;
            #pragma unroll
            for (int a = 0; a < 3; ++a) {
                float aw = c_aw[a], ah = c_ah[a];
                float inter = fminf(gw, aw) * fminf(gh, ah);
                float uni = gw * gh + 1e-16f + aw * ah - inter;
                float iou = inter / uni;
                ious[a] = iou;
                if (iou > bi) { bi = iou; best = a; }   // first-wins tie (argmax)
            }

            // ignore-clear: reference indexes noobj[b, :, gi, gj] -> H<-gi, W<-gj
            if (gi == i && gj == j) {
                #pragma unroll
                for (int a = 0; a < 3; ++a)
                    if (ious[a] > 0.5f) cleared |= (1 << a);
            }
            // main update at (b, best, gj, gi) -> H<-gj, W<-gi
            if (gj == i && gi == j) {
                cleared |= (1 << best);
                owner[best] = t;                         // last writer wins
                cmask[best][cls >> 5] |= (1u << (cls & 31));
            }
        }

        #pragma unroll
        for (int a = 0; a < 3; ++a) {
            bool obj = owner[a] >= 0;
            bool noobj = !((cleared >> a) & 1);          // obj => cleared => !noobj
            if (!obj && !noobj) continue;

            const float* pc = pred + (size_t)((b * AA + a) * BA_) * SPAT + s;
            float z = pc[4 * SPAT];
            float conf = 1.f / (1.f + expf(-z));
            if (noobj) {
                s_cn += 1.f;
                s_bn += -fmaxf(log1pf(-conf), -100.f);   // tconf = 0
            } else {
                s_co += 1.f;
                s_bo += -fmaxf(logf(conf), -100.f);      // tconf = 1
                const float* tg = tb + owner[a] * 5;
                float gx = tg[0] * WW, gy = tg[1] * HH;
                float gw = tg[2] * WW, gh = tg[3] * HH;
                float txv = gx - (float)j;               // j == adjusted gi
                float tyv = gy - (float)i;               // i == adjusted gj
                float twv = logf(gw / c_aw[a] + 1e-16f);
                float thv = logf(gh / c_ah[a] + 1e-16f);
                float x  = 1.f / (1.f + expf(-pc[0]));
                float y  = 1.f / (1.f + expf(-pc[SPAT]));
                float w_ = pc[2 * SPAT];
                float h_ = pc[3 * SPAT];
                s_mse += (x - txv) * (x - txv) + (y - tyv) * (y - tyv)
                       + (w_ - twv) * (w_ - twv) + (h_ - thv) * (h_ - thv);
                unsigned m0 = cmask[a][0], m1 = cmask[a][1], m2 = cmask[a][2];
                for (int c = 0; c < CC; ++c) {
                    float zc = pc[(5 + c) * SPAT];
                    float p  = 1.f / (1.f + expf(-zc));
                    float lp  = fmaxf(logf(p), -100.f);
                    float l1p = fmaxf(log1pf(-p), -100.f);
                    unsigned w = (c < 32) ? m0 : ((c < 64) ? m1 : m2);
                    s_bc += ((w >> (c & 31)) & 1) ? -lp : -l1p;
                }
            }
        }
    }

    // wave -> block -> global reduction (all threads participate)
    s_mse = wave_red(s_mse); s_bo = wave_red(s_bo); s_bn = wave_red(s_bn);
    s_bc  = wave_red(s_bc);  s_co = wave_red(s_co); s_cn = wave_red(s_cn);

    __shared__ float lds[4][6];
    int wave = threadIdx.x >> 6;
    if ((threadIdx.x & 63) == 0) {
        lds[wave][0] = s_mse; lds[wave][1] = s_bo; lds[wave][2] = s_bn;
        lds[wave][3] = s_bc;  lds[wave][4] = s_co; lds[wave][5] = s_cn;
    }
    __syncthreads();
    if (threadIdx.x == 0) {
        float v[6];
        #pragma unroll
        for (int k = 0; k < 6; ++k)
            v[k] = lds[0][k] + lds[1][k] + lds[2][k] + lds[3][k];
        atomicAdd(&acc[0], v[0]); atomicAdd(&acc[1], v[1]);
        atomicAdd(&acc[2], v[2]); atomicAdd(&acc[3], v[3]);
        atomicAdd(&acc[4], v[4]); atomicAdd(&acc[5], v[5]);
    }
}

__global__ void k_final(const float* __restrict__ acc, float* __restrict__ out) {
    float n_obj   = fmaxf(acc[4], 1.f);
    float n_noobj = fmaxf(acc[5], 1.f);
    out[0] = acc[0] / n_obj                      // x+y+w+h MSE
           + acc[1] / n_obj                      // OBJ_SCALE * conf-obj BCE
           + 100.f * (acc[2] / n_noobj)          // NOOBJ_SCALE * conf-noobj BCE
           + acc[3] / (n_obj * (float)CC);       // class BCE
}

extern "C" void kernel_launch(void* const* d_in, const int* in_sizes, int n_in,
                              void* d_out, int out_size, void* d_ws, size_t ws_size,
                              hipStream_t stream) {
    const float* pred    = (const float*)d_in[0];
    const float* targets = (const float*)d_in[1];
    float* out = (float*)d_out;
    float* acc = (float*)d_ws;      // 6 floats used; ws re-poisoned every launch

    hipMemsetAsync(acc, 0, 64, stream);

    dim3 grid((SPAT + 255) / 256, BB);   // 23 x 16 blocks
    k_loss<<<grid, 256, 0, stream>>>(pred, targets, acc);
    k_final<<<1, 1, 0, stream>>>(acc, out);
}